// Round 16
// baseline (273.143 us; speedup 1.0000x reference)
//
#include <hip/hip_runtime.h>

#define N_NODES 8192
#define N_EDGES 8192
#define DEG 32
#define CAP 128     // fixed CSR slots per node (Poisson(32); P(deg>128) ~ 0)
#define GRID 1024   // 4 blocks/CU, 0 LDS, <=128 VGPR -> full co-residency
#define IPB 8       // rows/edges/nodes per block
#define NCHUNK 32   // two-level barrier: 32 chunks x 32 blocks

typedef float vf4 __attribute__((ext_vector_type(4)));

// Two-level grid barrier. Counters pre-zeroed by host memset. Raw s_barriers
// (no vmcnt drain!) so fill waves' in-flight stores keep draining. Compute
// waves drain their own vmcnt before arrival (per-wave counter). Release on
// arrive publishes the block's writes (L2 writeback); acquire on exit
// invalidates (cross-XCD visibility). R7 validated AGENT-scope correctness.
__device__ __forceinline__ void gbar(int* bar, int ph) {
    asm volatile("" ::: "memory");
    __builtin_amdgcn_s_barrier();
    if (threadIdx.x == 0) {
        int* ccnt = bar + 3 + ph * NCHUNK + (blockIdx.x >> 5);
        int* root = bar + ph;
        if (__hip_atomic_fetch_add(ccnt, 1, __ATOMIC_ACQ_REL,
                                   __HIP_MEMORY_SCOPE_AGENT) == 31)
            __hip_atomic_fetch_add(root, 1, __ATOMIC_ACQ_REL,
                                   __HIP_MEMORY_SCOPE_AGENT);
        while (__hip_atomic_load(root, __ATOMIC_RELAXED,
                                 __HIP_MEMORY_SCOPE_AGENT) < NCHUNK)
            __builtin_amdgcn_s_sleep(1);
        (void)__hip_atomic_load(root, __ATOMIC_ACQUIRE,
                                __HIP_MEMORY_SCOPE_AGENT);
    }
    __builtin_amdgcn_s_barrier();
    asm volatile("" ::: "memory");
}

// Algebra: M = Wm1@Wm2@Wm3 split M0/M1; c = bm1@(Wm2@Wm3)+bm2@Wm3+bm3;
// v_y = Wl1@(Wl2@M0); v_z = Wl1@M1. ya[e]=A1[e]·v_y, za[e]=A1[e]·v_z;
// y[n]=Σ_CSR ya, z[n]=Σ_CSR za; qw[e]=Σ_{n∈e}y, q[e]=Σ_{n∈e}z;
// p[n]=c+Σ_CSR qw; out[n,e]=p[n]+q[e] at nonzeros else 0.
__global__ void __launch_bounds__(256, 4)
k_mono(const float* __restrict__ x0, const float* __restrict__ Wl1,
       const float* __restrict__ Wl2, const float* __restrict__ Wm1,
       const float* __restrict__ bm1, const float* __restrict__ Wm2,
       const float* __restrict__ bm2, const float* __restrict__ Wm3,
       const float* __restrict__ bm3, const int* __restrict__ node_idx,
       int* __restrict__ cursor, int* __restrict__ bar,
       unsigned* __restrict__ validmask,
       float* __restrict__ ya, float* __restrict__ za,
       float* __restrict__ y, float* __restrict__ z,
       float* __restrict__ qw, float* __restrict__ q,
       int* __restrict__ csr_e, float* __restrict__ out) {
    const int t = threadIdx.x, b = blockIdx.x;
    const bool isfill = (t >= 128);   // waves 2,3
    const int s = t & 31;
    const int lanebase = t & 32;      // group offset within wave for shfl
    const int el = t >> 5;            // 0..3 for compute threads

    float vy = 0.f, vz = 0.f, c = 0.f;

    if (isfill) {
        // ---- fill waves: issue 8 rows (256 KB) of zeros; no waits ----
        const int f = t - 128;
        vf4* dst = (vf4*)(out + (size_t)b * IPB * N_EDGES);
        vf4 zz = (vf4)(0.f);
#pragma unroll 8
        for (int k = 0; k < 128; ++k)
            dst[f + 128 * k] = zz;
    } else {
        // ---- in-register weight fold (per wave, shfl-based, no LDS) ----
        float w3 = Wm3[s];
        float w23 = 0.f;
        for (int k = 0; k < 32; ++k) w23 += Wm2[s * 32 + k] * Wm3[k];
        float M0 = 0.f, M1 = 0.f;
        for (int k = 0; k < 32; ++k) {
            float wk = __shfl(w23, lanebase + k);
            M0 += Wm1[s * 32 + k] * wk;
            M1 += Wm1[(32 + s) * 32 + k] * wk;
        }
        float w2u = 0.f;
        for (int k = 0; k < 32; ++k) w2u += Wl2[s * 32 + k] * __shfl(M0, lanebase + k);
        for (int k = 0; k < 32; ++k) {
            float wl = Wl1[s * 32 + k];
            vy += wl * __shfl(w2u, lanebase + k);
            vz += wl * __shfl(M1, lanebase + k);
        }
        float cp = bm1[s] * w23 + bm2[s] * w3;
#pragma unroll
        for (int off = 16; off; off >>= 1) cp += __shfl_xor(cp, off);
        c = cp + bm3[0];

        // ---- P1: edge-agg, dedup mask, CSR fill, ya/za (2 x 4 edges) ----
        for (int it = 0; it < 2; ++it) {
            int e = b * IPB + it * 4 + el;
            int idx = node_idx[e * DEG + s];
            bool valid = true;
            for (int j = 0; j < 32; ++j) {
                int idxj = __shfl(idx, lanebase + j);
                if (j < s && idxj == idx) valid = false;
            }
            unsigned long long bl = __ballot(valid);
            unsigned m = (unsigned)(bl >> lanebase);
            if (s == 0) validmask[e] = m;
            if (valid) {
                int pos = atomicAdd(&cursor[idx], 1);
                if (pos < CAP) csr_e[idx * CAP + pos] = e;
            }
            float acc = 0.f;
            for (int j = 0; j < 32; ++j) {
                int idxj = __shfl(idx, lanebase + j);
                if ((m >> j) & 1u) acc += x0[idxj * 32 + s];
            }
            float ay = acc * vy, az = acc * vz;
#pragma unroll
            for (int off = 16; off; off >>= 1) {
                ay += __shfl_xor(ay, off);
                az += __shfl_xor(az, off);
            }
            if (s == 0) { ya[e] = ay; za[e] = az; }
        }
        asm volatile("s_waitcnt vmcnt(0)" ::: "memory");  // own P1 writes drained
    }
    gbar(bar, 0);

    // ---- P2: y[n], z[n] via scalar CSR gather (compute waves) ----
    if (!isfill) {
        for (int it = 0; it < 2; ++it) {
            int n = b * IPB + it * 4 + el;
            int cnt = min(cursor[n], CAP);
            const int* lst = csr_e + n * CAP;
            float yy = 0.f, zz2 = 0.f;
            for (int j = s; j < cnt; j += 32) {
                int ee = lst[j];
                yy += ya[ee];
                zz2 += za[ee];
            }
#pragma unroll
            for (int off = 16; off; off >>= 1) {
                yy += __shfl_xor(yy, off);
                zz2 += __shfl_xor(zz2, off);
            }
            if (s == 0) { y[n] = yy; z[n] = zz2; }
        }
        asm volatile("s_waitcnt vmcnt(0)" ::: "memory");
    }
    gbar(bar, 1);

    // ---- P3: qw[e], q[e] (compute waves) ----
    if (!isfill) {
        for (int it = 0; it < 2; ++it) {
            int e = b * IPB + it * 4 + el;
            unsigned m = validmask[e];
            int idx = node_idx[e * DEG + s];
            bool valid = (m >> s) & 1u;
            float ay = valid ? y[idx] : 0.f;
            float az = valid ? z[idx] : 0.f;
#pragma unroll
            for (int off = 16; off; off >>= 1) {
                ay += __shfl_xor(ay, off);
                az += __shfl_xor(az, off);
            }
            if (s == 0) { qw[e] = ay; q[e] = az; }
        }
        asm volatile("s_waitcnt vmcnt(0)" ::: "memory");
    }
    gbar(bar, 2);

    // Full drain: fill waves' stores complete before patch touches the rows.
    __syncthreads();

    // ---- patch: p = c + sum qw; out[n,e] = p + q[e] (L2-hot lines) ----
    if (!isfill) {
        for (int it = 0; it < 2; ++it) {
            int n = b * IPB + it * 4 + el;
            int cnt = min(cursor[n], CAP);
            const int* lst = csr_e + n * CAP;
            float pp = 0.f;
            for (int j = s; j < cnt; j += 32) pp += qw[lst[j]];
#pragma unroll
            for (int off = 16; off; off >>= 1) pp += __shfl_xor(pp, off);
            float pn = pp + c;
            float* rowp = out + (size_t)n * N_EDGES;
            for (int j = s; j < cnt; j += 32) {
                int col = lst[j];
                rowp[col] = pn + q[col];
            }
        }
    }
}

extern "C" void kernel_launch(void* const* d_in, const int* in_sizes, int n_in,
                              void* d_out, int out_size, void* d_ws, size_t ws_size,
                              hipStream_t stream) {
    const float* x0  = (const float*)d_in[0];
    // d_in[1] = dense incidence matrix: unused (sparse path).
    const float* Wl1 = (const float*)d_in[2];
    const float* Wl2 = (const float*)d_in[3];
    const float* Wm1 = (const float*)d_in[4];
    const float* bm1 = (const float*)d_in[5];
    const float* Wm2 = (const float*)d_in[6];
    const float* bm2 = (const float*)d_in[7];
    const float* Wm3 = (const float*)d_in[8];
    const float* bm3 = (const float*)d_in[9];
    const int* node_idx = (const int*)d_in[10];
    float* out = (float*)d_out;

    // Workspace layout
    char* ws = (char*)d_ws;
    int*      cursor    = (int*)(ws);                     // 32 KB
    int*      bar       = (int*)(ws + (32u << 10));       // 512 B (3 roots + 3x32 chunks)
    unsigned* validmask = (unsigned*)(ws + (64u << 10));  // 32 KB
    float*    ya        = (float*)(ws + ( 96u << 10));    // 32 KB
    float*    za        = (float*)(ws + (128u << 10));    // 32 KB
    float*    y         = (float*)(ws + (160u << 10));    // 32 KB
    float*    z         = (float*)(ws + (192u << 10));    // 32 KB
    float*    qw        = (float*)(ws + (224u << 10));    // 32 KB
    float*    q         = (float*)(ws + (256u << 10));    // 32 KB
    int*      csr_e     = (int*)(ws + (1u << 20));        // 4 MB [N*CAP]

    // Zero cursor + barrier counters in one fill.
    hipMemsetAsync(cursor, 0, (32u << 10) + 512, stream);
    k_mono<<<GRID, 256, 0, stream>>>(x0, Wl1, Wl2, Wm1, bm1, Wm2, bm2, Wm3, bm3,
                                     node_idx, cursor, bar, validmask,
                                     ya, za, y, z, qw, q, csr_e, out);
}

// Round 17
// 91.969 us; speedup vs baseline: 2.9699x; 2.9699x over previous
//
#include <hip/hip_runtime.h>

#define N_NODES 8192
#define N_EDGES 8192
#define DEG 32
#define D 32
#define CAP 128   // fixed CSR slots per node (Poisson(32); P(deg>128) ~ 0)
#define HALF 4096 // columns per k3 block (half a row)

typedef float vf4 __attribute__((ext_vector_type(4)));

// Algebra (full collapse):
//   M = Wm1@Wm2@Wm3 (64x1), split M0 (node half) / M1 (edge half);
//   c = bm1@(Wm2@Wm3) + bm2@Wm3 + bm3
//   w2u = Wl2@M0 ;  v_y = Wl1@w2u ;  v_z = Wl1@M1
//   A1[e]  = sum_{unique n in e} x0[n]
//   B1[n]  = sum_{e in CSR[n]} A1[e] ;  y[n] = B1·v_y ; z[n] = B1·v_z
//   qw[e]  = sum_{n' in e} y[n'] ;  q[e] = sum_{n' in e} z[n']
//   p[n]   = c + sum_{e in CSR[n]} qw[e]
//   out[n,e] = p[n] + q[e] at incidence nonzeros, else 0.

// ---------------------------------------------------------------------------
// K1: block 0 folds weights into consts; all blocks: edge-agg1
// (dedup mask + CSR fill + A1). 8 edges/block, 32 lanes/edge.
// ---------------------------------------------------------------------------
__global__ void __launch_bounds__(256)
k1_edge(const float* __restrict__ x0, const float* __restrict__ Wl1,
        const float* __restrict__ Wl2, const float* __restrict__ Wm1,
        const float* __restrict__ bm1, const float* __restrict__ Wm2,
        const float* __restrict__ bm2, const float* __restrict__ Wm3,
        const float* __restrict__ bm3, const int* __restrict__ node_idx,
        float* __restrict__ A, unsigned* __restrict__ validmask,
        int* __restrict__ cursor, int* __restrict__ csr_e,
        float* __restrict__ consts) {
    __shared__ int sidx[8][32];
    __shared__ unsigned smask[8];
    __shared__ float fsh[128];
    const int t = threadIdx.x, el = t >> 5, s = t & 31;

    if (blockIdx.x == 0) {
        float* w23 = fsh;        // 32
        float* M0  = fsh + 32;   // 32
        float* M1  = fsh + 64;   // 32
        float* w2u = fsh + 96;   // 32
        if (t < 32) {
            float acc = 0.f;
            for (int k = 0; k < 32; ++k) acc += Wm2[t * 32 + k] * Wm3[k];
            w23[t] = acc;
        }
        __syncthreads();
        if (t < 64) {
            float acc = 0.f;
            for (int k = 0; k < 32; ++k) acc += Wm1[t * 32 + k] * w23[k];
            if (t < 32) M0[t] = acc; else M1[t - 32] = acc;
        }
        if (t == 0) {
            float c = bm3[0];
            for (int k = 0; k < 32; ++k) c += bm1[k] * w23[k] + bm2[k] * Wm3[k];
            consts[0] = c;
        }
        __syncthreads();
        if (t < 32) {
            float acc = 0.f;
            for (int d2 = 0; d2 < 32; ++d2) acc += Wl2[t * 32 + d2] * M0[d2];
            w2u[t] = acc;
        }
        __syncthreads();
        if (t < 32) {
            float ay = 0.f, az = 0.f;
            for (int d2 = 0; d2 < 32; ++d2) {
                float w = Wl1[t * 32 + d2];
                ay += w * w2u[d2];
                az += w * M1[d2];
            }
            consts[1 + t]  = ay;   // v_y
            consts[33 + t] = az;   // v_z
        }
        __syncthreads();
    }

    // ---- edge-agg1 ----
    int e = blockIdx.x * 8 + el;
    int idx = node_idx[e * DEG + s];
    sidx[el][s] = idx;
    __syncthreads();
    bool valid = true;
    for (int j = 0; j < s; ++j)
        if (sidx[el][j] == idx) { valid = false; break; }
    unsigned long long bl = __ballot(valid);
    if (s == 0) {
        unsigned m = (unsigned)(bl >> (t & 32));
        smask[el] = m;
        validmask[e] = m;
    }
    if (valid) {
        int pos = atomicAdd(&cursor[idx], 1);
        if (pos < CAP) csr_e[idx * CAP + pos] = e;
    }
    __syncthreads();
    unsigned m = smask[el];
    float acc = 0.f;
#pragma unroll
    for (int j = 0; j < 32; ++j)
        if ((m >> j) & 1u) acc += x0[sidx[el][j] * D + s];
    A[e * D + s] = acc;
}

// ---------------------------------------------------------------------------
// K2a: per node, B1 = sum of A1 rows in CSR[n]; y[n] = B1·v_y, z[n] = B1·v_z.
// 8 nodes/block, 32 lanes/node. Coalesced gathers, no atomics.
// ---------------------------------------------------------------------------
__global__ void __launch_bounds__(256)
k2_node(const float* __restrict__ A, const int* __restrict__ csr_e,
        const int* __restrict__ cursor, const float* __restrict__ consts,
        float* __restrict__ y, float* __restrict__ z) {
    const int t = threadIdx.x, el = t >> 5, s = t & 31;
    int n = blockIdx.x * 8 + el;
    int cnt = min(cursor[n], CAP);
    const int* lst = csr_e + n * CAP;
    float acc = 0.f;
    int j = 0;
    for (; j + 4 <= cnt; j += 4) {
        int4 e4 = *(const int4*)(lst + j);
        acc += A[e4.x * D + s] + A[e4.y * D + s] +
               A[e4.z * D + s] + A[e4.w * D + s];
    }
    for (; j < cnt; ++j) acc += A[lst[j] * D + s];
    float ay = acc * consts[1 + s];
    float az = acc * consts[33 + s];
#pragma unroll
    for (int off = 16; off; off >>= 1) {
        ay += __shfl_xor(ay, off);
        az += __shfl_xor(az, off);
    }
    if (s == 0) { y[n] = ay; z[n] = az; }
}

// ---------------------------------------------------------------------------
// K2b: per edge, qw[e] = sum of y over valid member nodes; q[e] = same for z.
// 8 edges/block, 32 lanes/edge; y/z tables are 32 KB (L1/L2-hot).
// ---------------------------------------------------------------------------
__global__ void __launch_bounds__(256)
k2_edge(const int* __restrict__ node_idx, const unsigned* __restrict__ validmask,
        const float* __restrict__ y, const float* __restrict__ z,
        float* __restrict__ qw, float* __restrict__ q) {
    const int t = threadIdx.x, el = t >> 5, s = t & 31;
    int e = blockIdx.x * 8 + el;
    unsigned m = validmask[e];
    int idx = node_idx[e * DEG + s];
    bool valid = (m >> s) & 1u;
    float ay = valid ? y[idx] : 0.f;
    float az = valid ? z[idx] : 0.f;
#pragma unroll
    for (int off = 16; off; off >>= 1) {
        ay += __shfl_xor(ay, off);
        az += __shfl_xor(az, off);
    }
    if (s == 0) { qw[e] = ay; q[e] = az; }
}

// ---------------------------------------------------------------------------
// K3: two blocks per output row (16 KB half-row in LDS each, 8 blocks/CU).
// Compose half-row in LDS (zeros + patches), then stream it out with
// NONTEMPORAL float4 stores (single-variable change vs R12: tests whether
// d_out's ~4.9 TB/s write rate is write-allocate/L3-retention policy that
// NT bypasses; same loop hits 6.5 TB/s on d_ws).
// ---------------------------------------------------------------------------
__global__ void __launch_bounds__(256)
k3_out(const int* __restrict__ csr_e, const int* __restrict__ cursor,
       const float* __restrict__ qw, const float* __restrict__ q,
       const float* __restrict__ consts, float* __restrict__ out) {
    __shared__ float row[HALF];   // 16 KB half-row
    __shared__ int eid[CAP];
    __shared__ float sp;
    const int t = threadIdx.x;
    const int n = blockIdx.x >> 1;
    const int h = blockIdx.x & 1;          // which half of the row
    const int base = h * HALF;
    const int cnt = min(cursor[n], CAP);
    if (t < CAP) eid[t] = csr_e[n * CAP + t];
    vf4* r4 = (vf4*)row;
    vf4 zz = (vf4)(0.f);
#pragma unroll
    for (int k = 0; k < 4; ++k) r4[t + 256 * k] = zz;
    __syncthreads();
    // p[n] = c + sum qw[eid]  (full sum; duplicated across both halves)
    if (t < 32) {
        float v = 0.f;
        for (int j = t; j < cnt; j += 32) v += qw[eid[j]];
#pragma unroll
        for (int off = 16; off; off >>= 1) v += __shfl_xor(v, off);
        if (t == 0) sp = v + consts[0];
    }
    __syncthreads();
    float pn = sp;
    for (int j = t; j < cnt; j += 256) {
        int e = eid[j];
        int le = e - base;
        if ((unsigned)le < (unsigned)HALF) row[le] = pn + q[e];
    }
    __syncthreads();
    vf4* g4 = (vf4*)(out + (size_t)n * N_EDGES + base);
#pragma unroll
    for (int k = 0; k < 4; ++k)
        __builtin_nontemporal_store(r4[t + 256 * k], &g4[t + 256 * k]);
}

extern "C" void kernel_launch(void* const* d_in, const int* in_sizes, int n_in,
                              void* d_out, int out_size, void* d_ws, size_t ws_size,
                              hipStream_t stream) {
    const float* x0  = (const float*)d_in[0];
    // d_in[1] = dense incidence matrix: unused (sparse path).
    const float* Wl1 = (const float*)d_in[2];
    const float* Wl2 = (const float*)d_in[3];
    const float* Wm1 = (const float*)d_in[4];
    const float* bm1 = (const float*)d_in[5];
    const float* Wm2 = (const float*)d_in[6];
    const float* bm2 = (const float*)d_in[7];
    const float* Wm3 = (const float*)d_in[8];
    const float* bm3 = (const float*)d_in[9];
    const int* node_idx = (const int*)d_in[10];
    float* out = (float*)d_out;

    // Workspace layout
    char* ws = (char*)d_ws;
    int*      cursor    = (int*)(ws);                          // 32 KB
    float*    y         = (float*)(ws + ( 32u << 10));         // 32 KB
    float*    z         = (float*)(ws + ( 64u << 10));         // 32 KB
    unsigned* validmask = (unsigned*)(ws + ( 96u << 10));      // 32 KB
    float*    qw        = (float*)(ws + (128u << 10));         // 32 KB
    float*    q         = (float*)(ws + (160u << 10));         // 32 KB
    float*    consts    = (float*)(ws + (192u << 10));         // 65 floats
    float*    A         = (float*)(ws + (1u << 20));           // 1 MB [E*D]
    int*      csr_e     = (int*)(ws + (2u << 20));             // 4 MB [N*CAP]

    hipMemsetAsync(cursor, 0, N_NODES * sizeof(int), stream);
    k1_edge<<<N_EDGES / 8, 256, 0, stream>>>(x0, Wl1, Wl2, Wm1, bm1, Wm2, bm2,
                                             Wm3, bm3, node_idx, A, validmask,
                                             cursor, csr_e, consts);
    k2_node<<<N_NODES / 8, 256, 0, stream>>>(A, csr_e, cursor, consts, y, z);
    k2_edge<<<N_EDGES / 8, 256, 0, stream>>>(node_idx, validmask, y, z, qw, q);
    k3_out<<<2 * N_NODES, 256, 0, stream>>>(csr_e, cursor, qw, q, consts, out);
}

// Round 18
// 81.864 us; speedup vs baseline: 3.3365x; 1.1234x over previous
//
#include <hip/hip_runtime.h>

#define N_NODES 8192
#define N_EDGES 8192
#define DEG 32
#define D 32
#define CAP 128   // fixed CSR slots per node (Poisson(32); P(deg>128) ~ 0)
#define HALF 4096 // columns per k3 block (half a row)

typedef float vf4 __attribute__((ext_vector_type(4)));

// Algebra (full collapse):
//   M = Wm1@Wm2@Wm3 (64x1), split M0 (node half) / M1 (edge half);
//   c = bm1@(Wm2@Wm3) + bm2@Wm3 + bm3
//   w2u = Wl2@M0 ;  v_y = Wl1@w2u ;  v_z = Wl1@M1
//   A1[e]  = sum_{unique n in e} x0[n]
//   B1[n]  = sum_{e in CSR[n]} A1[e] ;  y[n] = B1·v_y ; z[n] = B1·v_z
//   qw[e]  = sum_{n' in e} y[n'] ;  q[e] = sum_{n' in e} z[n']
//   p[n]   = c + sum_{e in CSR[n]} qw[e]
//   out[n,e] = p[n] + q[e] at incidence nonzeros, else 0.
//
// Structure (best measured, R12): serial 5-dispatch pipeline. Output pass =
// half-row LDS compose + plain float4 streaming stores at 8 blocks/CU.
// d_out write wall measured ~4.8 TB/s (vs 6.5 on d_ws; NT and rocclr fill
// are worse) -- the remaining time is that wall + minimal chain.

// ---------------------------------------------------------------------------
// K1: block 0 folds weights into consts; all blocks: edge-agg1
// (dedup mask + CSR fill + A1). 8 edges/block, 32 lanes/edge.
// ---------------------------------------------------------------------------
__global__ void __launch_bounds__(256)
k1_edge(const float* __restrict__ x0, const float* __restrict__ Wl1,
        const float* __restrict__ Wl2, const float* __restrict__ Wm1,
        const float* __restrict__ bm1, const float* __restrict__ Wm2,
        const float* __restrict__ bm2, const float* __restrict__ Wm3,
        const float* __restrict__ bm3, const int* __restrict__ node_idx,
        float* __restrict__ A, unsigned* __restrict__ validmask,
        int* __restrict__ cursor, int* __restrict__ csr_e,
        float* __restrict__ consts) {
    __shared__ int sidx[8][32];
    __shared__ unsigned smask[8];
    __shared__ float fsh[128];
    const int t = threadIdx.x, el = t >> 5, s = t & 31;

    if (blockIdx.x == 0) {
        float* w23 = fsh;        // 32
        float* M0  = fsh + 32;   // 32
        float* M1  = fsh + 64;   // 32
        float* w2u = fsh + 96;   // 32
        if (t < 32) {
            float acc = 0.f;
            for (int k = 0; k < 32; ++k) acc += Wm2[t * 32 + k] * Wm3[k];
            w23[t] = acc;
        }
        __syncthreads();
        if (t < 64) {
            float acc = 0.f;
            for (int k = 0; k < 32; ++k) acc += Wm1[t * 32 + k] * w23[k];
            if (t < 32) M0[t] = acc; else M1[t - 32] = acc;
        }
        if (t == 0) {
            float c = bm3[0];
            for (int k = 0; k < 32; ++k) c += bm1[k] * w23[k] + bm2[k] * Wm3[k];
            consts[0] = c;
        }
        __syncthreads();
        if (t < 32) {
            float acc = 0.f;
            for (int d2 = 0; d2 < 32; ++d2) acc += Wl2[t * 32 + d2] * M0[d2];
            w2u[t] = acc;
        }
        __syncthreads();
        if (t < 32) {
            float ay = 0.f, az = 0.f;
            for (int d2 = 0; d2 < 32; ++d2) {
                float w = Wl1[t * 32 + d2];
                ay += w * w2u[d2];
                az += w * M1[d2];
            }
            consts[1 + t]  = ay;   // v_y
            consts[33 + t] = az;   // v_z
        }
        __syncthreads();
    }

    // ---- edge-agg1 ----
    int e = blockIdx.x * 8 + el;
    int idx = node_idx[e * DEG + s];
    sidx[el][s] = idx;
    __syncthreads();
    bool valid = true;
    for (int j = 0; j < s; ++j)
        if (sidx[el][j] == idx) { valid = false; break; }
    unsigned long long bl = __ballot(valid);
    if (s == 0) {
        unsigned m = (unsigned)(bl >> (t & 32));
        smask[el] = m;
        validmask[e] = m;
    }
    if (valid) {
        int pos = atomicAdd(&cursor[idx], 1);
        if (pos < CAP) csr_e[idx * CAP + pos] = e;
    }
    __syncthreads();
    unsigned m = smask[el];
    float acc = 0.f;
#pragma unroll
    for (int j = 0; j < 32; ++j)
        if ((m >> j) & 1u) acc += x0[sidx[el][j] * D + s];
    A[e * D + s] = acc;
}

// ---------------------------------------------------------------------------
// K2a: per node, B1 = sum of A1 rows in CSR[n]; y[n] = B1·v_y, z[n] = B1·v_z.
// 8 nodes/block, 32 lanes/node. Coalesced gathers, no atomics.
// ---------------------------------------------------------------------------
__global__ void __launch_bounds__(256)
k2_node(const float* __restrict__ A, const int* __restrict__ csr_e,
        const int* __restrict__ cursor, const float* __restrict__ consts,
        float* __restrict__ y, float* __restrict__ z) {
    const int t = threadIdx.x, el = t >> 5, s = t & 31;
    int n = blockIdx.x * 8 + el;
    int cnt = min(cursor[n], CAP);
    const int* lst = csr_e + n * CAP;
    float acc = 0.f;
    int j = 0;
    for (; j + 4 <= cnt; j += 4) {
        int4 e4 = *(const int4*)(lst + j);
        acc += A[e4.x * D + s] + A[e4.y * D + s] +
               A[e4.z * D + s] + A[e4.w * D + s];
    }
    for (; j < cnt; ++j) acc += A[lst[j] * D + s];
    float ay = acc * consts[1 + s];
    float az = acc * consts[33 + s];
#pragma unroll
    for (int off = 16; off; off >>= 1) {
        ay += __shfl_xor(ay, off);
        az += __shfl_xor(az, off);
    }
    if (s == 0) { y[n] = ay; z[n] = az; }
}

// ---------------------------------------------------------------------------
// K2b: per edge, qw[e] = sum of y over valid member nodes; q[e] = same for z.
// 8 edges/block, 32 lanes/edge; y/z tables are 32 KB (L1/L2-hot).
// ---------------------------------------------------------------------------
__global__ void __launch_bounds__(256)
k2_edge(const int* __restrict__ node_idx, const unsigned* __restrict__ validmask,
        const float* __restrict__ y, const float* __restrict__ z,
        float* __restrict__ qw, float* __restrict__ q) {
    const int t = threadIdx.x, el = t >> 5, s = t & 31;
    int e = blockIdx.x * 8 + el;
    unsigned m = validmask[e];
    int idx = node_idx[e * DEG + s];
    bool valid = (m >> s) & 1u;
    float ay = valid ? y[idx] : 0.f;
    float az = valid ? z[idx] : 0.f;
#pragma unroll
    for (int off = 16; off; off >>= 1) {
        ay += __shfl_xor(ay, off);
        az += __shfl_xor(az, off);
    }
    if (s == 0) { qw[e] = ay; q[e] = az; }
}

// ---------------------------------------------------------------------------
// K3: two blocks per output row (16 KB half-row in LDS each, 8 blocks/CU =
// wave-limited full occupancy). Zero LDS half-row, p = c + sum qw[eid],
// patch in-range cells with p + q[eid], stream 16 KB out with plain float4
// stores (best measured d_out write structure: ~4.8 TB/s).
// ---------------------------------------------------------------------------
__global__ void __launch_bounds__(256)
k3_out(const int* __restrict__ csr_e, const int* __restrict__ cursor,
       const float* __restrict__ qw, const float* __restrict__ q,
       const float* __restrict__ consts, float* __restrict__ out) {
    __shared__ float row[HALF];   // 16 KB half-row
    __shared__ int eid[CAP];
    __shared__ float sp;
    const int t = threadIdx.x;
    const int n = blockIdx.x >> 1;
    const int h = blockIdx.x & 1;          // which half of the row
    const int base = h * HALF;
    const int cnt = min(cursor[n], CAP);
    if (t < CAP) eid[t] = csr_e[n * CAP + t];
    vf4* r4 = (vf4*)row;
    vf4 zz = (vf4)(0.f);
#pragma unroll
    for (int k = 0; k < 4; ++k) r4[t + 256 * k] = zz;
    __syncthreads();
    // p[n] = c + sum qw[eid]  (full sum; duplicated across both halves)
    if (t < 32) {
        float v = 0.f;
        for (int j = t; j < cnt; j += 32) v += qw[eid[j]];
#pragma unroll
        for (int off = 16; off; off >>= 1) v += __shfl_xor(v, off);
        if (t == 0) sp = v + consts[0];
    }
    __syncthreads();
    float pn = sp;
    for (int j = t; j < cnt; j += 256) {
        int e = eid[j];
        int le = e - base;
        if ((unsigned)le < (unsigned)HALF) row[le] = pn + q[e];
    }
    __syncthreads();
    vf4* g4 = (vf4*)(out + (size_t)n * N_EDGES + base);
#pragma unroll
    for (int k = 0; k < 4; ++k) g4[t + 256 * k] = r4[t + 256 * k];
}

extern "C" void kernel_launch(void* const* d_in, const int* in_sizes, int n_in,
                              void* d_out, int out_size, void* d_ws, size_t ws_size,
                              hipStream_t stream) {
    const float* x0  = (const float*)d_in[0];
    // d_in[1] = dense incidence matrix: unused (sparse path).
    const float* Wl1 = (const float*)d_in[2];
    const float* Wl2 = (const float*)d_in[3];
    const float* Wm1 = (const float*)d_in[4];
    const float* bm1 = (const float*)d_in[5];
    const float* Wm2 = (const float*)d_in[6];
    const float* bm2 = (const float*)d_in[7];
    const float* Wm3 = (const float*)d_in[8];
    const float* bm3 = (const float*)d_in[9];
    const int* node_idx = (const int*)d_in[10];
    float* out = (float*)d_out;

    // Workspace layout
    char* ws = (char*)d_ws;
    int*      cursor    = (int*)(ws);                          // 32 KB
    float*    y         = (float*)(ws + ( 32u << 10));         // 32 KB
    float*    z         = (float*)(ws + ( 64u << 10));         // 32 KB
    unsigned* validmask = (unsigned*)(ws + ( 96u << 10));      // 32 KB
    float*    qw        = (float*)(ws + (128u << 10));         // 32 KB
    float*    q         = (float*)(ws + (160u << 10));         // 32 KB
    float*    consts    = (float*)(ws + (192u << 10));         // 65 floats
    float*    A         = (float*)(ws + (1u << 20));           // 1 MB [E*D]
    int*      csr_e     = (int*)(ws + (2u << 20));             // 4 MB [N*CAP]

    hipMemsetAsync(cursor, 0, N_NODES * sizeof(int), stream);
    k1_edge<<<N_EDGES / 8, 256, 0, stream>>>(x0, Wl1, Wl2, Wm1, bm1, Wm2, bm2,
                                             Wm3, bm3, node_idx, A, validmask,
                                             cursor, csr_e, consts);
    k2_node<<<N_NODES / 8, 256, 0, stream>>>(A, csr_e, cursor, consts, y, z);
    k2_edge<<<N_EDGES / 8, 256, 0, stream>>>(node_idx, validmask, y, z, qw, q);
    k3_out<<<2 * N_NODES, 256, 0, stream>>>(csr_e, cursor, qw, q, consts, out);
}